// Round 1
// baseline (13509.344 us; speedup 1.0000x reference)
//
#include <hip/hip_runtime.h>
#include <hip/hip_bf16.h>
#include <stdint.h>

// Problem constants
#define HD    256      // hidden
#define G3    768      // 3*H
#define LL    50       // friend seq len
#define SS    50       // common seq len
#define NB    64       // batch
#define MAXF  32
#define NSEQ  2048     // NB*MAXF
#define MB    16       // sequences per block (one 16-row MFMA M-tile)
#define NBLK  128      // NSEQ/MB
#define XP    264      // padded LDS row length (bf16 elems) -> 528B rows, 16B aligned

typedef __attribute__((ext_vector_type(8))) short bf16x8;
typedef __attribute__((ext_vector_type(4))) float f32x4;

__device__ __forceinline__ f32x4 mfma16(bf16x8 a, bf16x8 b, f32x4 c) {
    return __builtin_amdgcn_mfma_f32_16x16x32_bf16(a, b, c, 0, 0, 0);
}

__device__ __forceinline__ unsigned short f2bf_rne(float f) {
    union { float f; uint32_t u; } v; v.f = f;
    uint32_t u = v.u;
    uint32_t r = u + 0x7FFFu + ((u >> 16) & 1u);
    return (unsigned short)(r >> 16);
}
__device__ __forceinline__ float bf2f(unsigned short b) {
    union { float f; uint32_t u; } v; v.u = ((uint32_t)b) << 16;
    return v.f;
}

// ---------------------------------------------------------------------------
// Pack: weights -> bf16 hi/lo planes in MFMA fragment order, plus Wf transpose.
// wpk layout: [l(2)][m(2: ih,hh)][nt(48)][c(8)][lane(64)][j(8)]
// fragment semantics: row n = nt*16 + (lane&15), k = c*32 + (lane>>4)*8 + j
// ---------------------------------------------------------------------------
__global__ void pack_kernel(const float* __restrict__ Wih0, const float* __restrict__ Whh0,
                            const float* __restrict__ Wih1, const float* __restrict__ Whh1,
                            const float* __restrict__ Wf,
                            unsigned short* __restrict__ wpk_hi,
                            unsigned short* __restrict__ wpk_lo,
                            float* __restrict__ WfT) {
    int idx = blockIdx.x * blockDim.x + threadIdx.x;
    const int total_w = 2 * 2 * 48 * 8 * 64 * 8;   // 786432
    if (idx < total_w) {
        int j    = idx & 7;
        int lane = (idx >> 3) & 63;
        int c    = (idx >> 9) & 7;
        int nt   = (idx >> 12) % 48;
        int lm   = idx / (48 * 8 * 64 * 8);         // 0..3 : Wih0,Whh0,Wih1,Whh1
        const float* W = (lm == 0) ? Wih0 : (lm == 1) ? Whh0 : (lm == 2) ? Wih1 : Whh1;
        int n = nt * 16 + (lane & 15);
        int k = c * 32 + (lane >> 4) * 8 + j;
        float v = W[n * HD + k];
        unsigned short hi = f2bf_rne(v);
        float rem = v - bf2f(hi);
        wpk_hi[idx] = hi;
        wpk_lo[idx] = f2bf_rne(rem);
    } else {
        int idx2 = idx - total_w;
        if (idx2 < 512 * 256) {                     // WfT[k][h] = Wf[h][k]
            int k = idx2 >> 8; int h = idx2 & 255;
            WfT[k * 256 + h] = Wf[h * 512 + k];
        }
    }
}

// ---------------------------------------------------------------------------
// Counting sort of the 2048 sequences by friend_len (1..50), ascending.
// Blocks then get near-uniform lengths and stop at their own maxlen.
// ---------------------------------------------------------------------------
__global__ void sort_kernel(const int* __restrict__ flen, int* __restrict__ sid) {
    __shared__ int hist[64];
    __shared__ int offs[64];
    int tid = threadIdx.x;
    if (tid < 64) hist[tid] = 0;
    __syncthreads();
    for (int i = tid; i < NSEQ; i += blockDim.x) atomicAdd(&hist[flen[i]], 1);
    __syncthreads();
    if (tid == 0) {
        int acc = 0;
        for (int v = 1; v <= 50; v++) { offs[v] = acc; acc += hist[v]; }
    }
    __syncthreads();
    for (int i = tid; i < NSEQ; i += blockDim.x) {
        int pos = atomicAdd(&offs[flen[i]], 1);
        sid[pos] = i;
    }
}

// ---------------------------------------------------------------------------
// Fused 2-layer GRU, 16 sequences per block, split-bf16 (hi+lo) MFMA.
// Wave w owns gate tiles {4w+i, 16+4w+i, 32+4w+i} i<4 -> j in [64w,64w+64).
// C-layout alignment lets gates be computed entirely in registers.
// ---------------------------------------------------------------------------
__global__ __launch_bounds__(256, 1)
void gru_kernel(const float* __restrict__ friend_x,
                const int* __restrict__ flen,
                const int* __restrict__ sid,
                const unsigned short* __restrict__ wpk_hi,
                const unsigned short* __restrict__ wpk_lo,
                const float* __restrict__ bih0, const float* __restrict__ bhh0,
                const float* __restrict__ bih1, const float* __restrict__ bhh1,
                float* __restrict__ friend_last) {
    __shared__ unsigned short Xhi[MB][XP],  Xlo[MB][XP];
    __shared__ unsigned short H0hi[MB][XP], H0lo[MB][XP];
    __shared__ unsigned short H1hi[MB][XP], H1lo[MB][XP];
    __shared__ int sidS[MB], lenS[MB];

    const int tid  = threadIdx.x;
    const int g    = blockIdx.x;
    const int wv   = tid >> 6;
    const int lane = tid & 63;

    if (tid < MB) {
        int s_ = sid[g * MB + tid];
        sidS[tid] = s_;
        lenS[tid] = flen[s_];
    }
    // zero hidden-state LDS
    for (int i = tid; i < MB * XP; i += 256) {
        (&H0hi[0][0])[i] = 0; (&H0lo[0][0])[i] = 0;
        (&H1hi[0][0])[i] = 0; (&H1lo[0][0])[i] = 0;
    }
    __syncthreads();

    int maxlen = 0;
#pragma unroll
    for (int s = 0; s < MB; s++) maxlen = max(maxlen, lenS[s]);

    const int qrow = (lane >> 4) * 4;   // seq base for this lane's acc regs
    const int cn   = lane & 15;         // column-within-tile

    // per-lane biases (combined for r/z; separate i/h for n-gate)
    float b0R[4], b0Z[4], b0NI[4], b0NH[4];
    float b1R[4], b1Z[4], b1NI[4], b1NH[4];
#pragma unroll
    for (int i = 0; i < 4; i++) {
        int j = wv * 64 + i * 16 + cn;
        b0R[i]  = bih0[j]       + bhh0[j];
        b0Z[i]  = bih0[256 + j] + bhh0[256 + j];
        b0NI[i] = bih0[512 + j];
        b0NH[i] = bhh0[512 + j];
        b1R[i]  = bih1[j]       + bhh1[j];
        b1Z[i]  = bih1[256 + j] + bhh1[256 + j];
        b1NI[i] = bih1[512 + j];
        b1NH[i] = bhh1[512 + j];
    }

    int myLen[4], mySid[4];
#pragma unroll
    for (int r = 0; r < 4; r++) { myLen[r] = lenS[qrow + r]; mySid[r] = sidS[qrow + r]; }

    float h0r[4][4], h1r[4][4];
#pragma unroll
    for (int i = 0; i < 4; i++)
#pragma unroll
        for (int r = 0; r < 4; r++) { h0r[i][r] = 0.f; h1r[i][r] = 0.f; }

    auto stageX = [&](int t) {
        int s = tid >> 4, seg = tid & 15;
        const float* src = friend_x + ((size_t)sidS[s] * LL + t) * HD + seg * 16;
#pragma unroll
        for (int q4 = 0; q4 < 4; q4++) {
            float4 f4 = ((const float4*)src)[q4];
            float vals[4] = { f4.x, f4.y, f4.z, f4.w };
#pragma unroll
            for (int e = 0; e < 4; e++) {
                int col = seg * 16 + q4 * 4 + e;
                unsigned short hi_ = f2bf_rne(vals[e]);
                Xhi[s][col] = hi_;
                Xlo[s][col] = f2bf_rne(vals[e] - bf2f(hi_));
            }
        }
    };

    auto loadFrag = [&](const unsigned short (*A)[XP], int c) -> bf16x8 {
        return *(const bf16x8*)&A[lane & 15][c * 32 + (lane >> 4) * 8];
    };
    auto loadB = [&](int l, int m, int nt, int c, int lo) -> bf16x8 {
        const unsigned short* base = lo ? wpk_lo : wpk_hi;
        int off = ((((l * 2 + m) * 48 + nt) * 8 + c) * 64 + lane) * 8;
        return *(const bf16x8*)(base + off);
    };

    auto doLayer = [&](int l, const bf16x8* xh, const bf16x8* xl,
                       const bf16x8* hh, const bf16x8* hl,
                       float (*hreg)[4],
                       const float* cbR, const float* cbZ,
                       const float* cbNI, const float* cbNH,
                       unsigned short (*Ohi)[XP], unsigned short (*Olo)[XP],
                       bool gather, int t) {
        const f32x4 z4 = { 0.f, 0.f, 0.f, 0.f };
        f32x4 aR[4], aZ[4], aNI[4], aNH[4];
#pragma unroll
        for (int i = 0; i < 4; i++) { aR[i] = z4; aZ[i] = z4; aNI[i] = z4; aNH[i] = z4; }

#pragma unroll
        for (int i = 0; i < 4; i++) {
            const int ntR = 4 * wv + i, ntZ = 16 + 4 * wv + i, ntN = 32 + 4 * wv + i;
#pragma unroll
            for (int c = 0; c < 8; c++) {
                // ---- input part (m=0, operand = x) ----
                {
                    bf16x8 bh = loadB(l, 0, ntR, c, 0), bl = loadB(l, 0, ntR, c, 1);
                    aR[i] = mfma16(xh[c], bh, aR[i]);
                    aR[i] = mfma16(xl[c], bh, aR[i]);
                    aR[i] = mfma16(xh[c], bl, aR[i]);
                }
                {
                    bf16x8 bh = loadB(l, 0, ntZ, c, 0), bl = loadB(l, 0, ntZ, c, 1);
                    aZ[i] = mfma16(xh[c], bh, aZ[i]);
                    aZ[i] = mfma16(xl[c], bh, aZ[i]);
                    aZ[i] = mfma16(xh[c], bl, aZ[i]);
                }
                {
                    bf16x8 bh = loadB(l, 0, ntN, c, 0), bl = loadB(l, 0, ntN, c, 1);
                    aNI[i] = mfma16(xh[c], bh, aNI[i]);
                    aNI[i] = mfma16(xl[c], bh, aNI[i]);
                    aNI[i] = mfma16(xh[c], bl, aNI[i]);
                }
                // ---- hidden part (m=1, operand = h) ----
                {
                    bf16x8 bh = loadB(l, 1, ntR, c, 0), bl = loadB(l, 1, ntR, c, 1);
                    aR[i] = mfma16(hh[c], bh, aR[i]);
                    aR[i] = mfma16(hl[c], bh, aR[i]);
                    aR[i] = mfma16(hh[c], bl, aR[i]);
                }
                {
                    bf16x8 bh = loadB(l, 1, ntZ, c, 0), bl = loadB(l, 1, ntZ, c, 1);
                    aZ[i] = mfma16(hh[c], bh, aZ[i]);
                    aZ[i] = mfma16(hl[c], bh, aZ[i]);
                    aZ[i] = mfma16(hh[c], bl, aZ[i]);
                }
                {
                    bf16x8 bh = loadB(l, 1, ntN, c, 0), bl = loadB(l, 1, ntN, c, 1);
                    aNH[i] = mfma16(hh[c], bh, aNH[i]);
                    aNH[i] = mfma16(hl[c], bh, aNH[i]);
                    aNH[i] = mfma16(hh[c], bl, aNH[i]);
                }
            }
        }
        // gates: C-layout row = (lane>>4)*4 + r  (== sequence), col = cn
#pragma unroll
        for (int i = 0; i < 4; i++) {
            const int j = wv * 64 + i * 16 + cn;
#pragma unroll
            for (int r = 0; r < 4; r++) {
                float pre_r = aR[i][r]  + cbR[i];
                float pre_z = aZ[i][r]  + cbZ[i];
                float gin   = aNI[i][r] + cbNI[i];
                float ghn   = aNH[i][r] + cbNH[i];
                float rr = 1.f / (1.f + __expf(-pre_r));
                float zz = 1.f / (1.f + __expf(-pre_z));
                float nx = gin + rr * ghn;
                float e  = __expf(-2.f * fabsf(nx));
                float th = 1.f - 2.f * e / (1.f + e);
                th = (nx < 0.f) ? -th : th;
                float hNew = (1.f - zz) * th + zz * hreg[i][r];
                hreg[i][r] = hNew;
                int s = qrow + r;
                unsigned short hi_ = f2bf_rne(hNew);
                Ohi[s][j] = hi_;
                Olo[s][j] = f2bf_rne(hNew - bf2f(hi_));
                if (gather && t == myLen[r] - 1)
                    friend_last[(size_t)mySid[r] * HD + j] = hNew;
            }
        }
    };

    stageX(0);
    __syncthreads();

    for (int t = 0; t < maxlen; t++) {
        bf16x8 xh[8], xl[8], hh[8], hl[8];
        // Layer 0: A = [x(t) | h0]
#pragma unroll
        for (int c = 0; c < 8; c++) {
            xh[c] = loadFrag(Xhi, c);  xl[c] = loadFrag(Xlo, c);
            hh[c] = loadFrag(H0hi, c); hl[c] = loadFrag(H0lo, c);
        }
        __syncthreads();                     // all waves hoisted; X/H0 now writable
        if (t + 1 < maxlen) stageX(t + 1);   // overlap next-step staging with MFMA
        doLayer(0, xh, xl, hh, hl, h0r, b0R, b0Z, b0NI, b0NH, H0hi, H0lo, false, t);
        __syncthreads();                     // h0(t) visible
        // Layer 1: A = [h0(t) | h1]
#pragma unroll
        for (int c = 0; c < 8; c++) {
            xh[c] = loadFrag(H0hi, c); xl[c] = loadFrag(H0lo, c);
            hh[c] = loadFrag(H1hi, c); hl[c] = loadFrag(H1lo, c);
        }
        __syncthreads();                     // H1 writable
        doLayer(1, xh, xl, hh, hl, h1r, b1R, b1Z, b1NI, b1NH, H1hi, H1lo, true, t);
        __syncthreads();                     // h1(t) visible for next iteration
    }
}

// ---------------------------------------------------------------------------
// sf[n,h] = Wf[h,:256]·self_x[b] + Wf[h,256:]·friend_last[n]   (fp32 exact)
// ---------------------------------------------------------------------------
__global__ __launch_bounds__(256)
void sf_kernel(const float* __restrict__ self_x, const float* __restrict__ fl,
               const float* __restrict__ WfT, float* __restrict__ sf) {
    __shared__ float S[256];
    __shared__ float FLT[256][36];   // [k][f], padded
    int b = blockIdx.x, tid = threadIdx.x;
    S[tid] = self_x[b * 256 + tid];
    for (int i = tid; i < 32 * 256; i += 256) {
        int f = i >> 8, k = i & 255;
        FLT[k][f] = fl[((size_t)(b * 32 + f)) * 256 + k];
    }
    __syncthreads();
    float acc0 = 0.f;
    for (int k = 0; k < 256; k++) acc0 += WfT[k * 256 + tid] * S[k];
    float acc[32];
#pragma unroll
    for (int f = 0; f < 32; f++) acc[f] = acc0;
    for (int k = 0; k < 256; k++) {
        float w = WfT[(256 + k) * 256 + tid];
#pragma unroll
        for (int f4 = 0; f4 < 8; f4++) {
            float4 x4 = ((const float4*)&FLT[k][0])[f4];
            acc[f4 * 4 + 0] += w * x4.x;
            acc[f4 * 4 + 1] += w * x4.y;
            acc[f4 * 4 + 2] += w * x4.z;
            acc[f4 * 4 + 3] += w * x4.w;
        }
    }
#pragma unroll
    for (int f = 0; f < 32; f++)
        sf[((size_t)(b * 32 + f)) * 256 + tid] = acc[f];
}

// ---------------------------------------------------------------------------
// v[n,h] = sum_g Wb[g,h] * sf[n,g]
// ---------------------------------------------------------------------------
__global__ __launch_bounds__(256)
void v_kernel(const float* __restrict__ sf, const float* __restrict__ Wb,
              float* __restrict__ vout) {
    __shared__ float SFT[256][36];   // [g][f]
    int b = blockIdx.x, tid = threadIdx.x;
    for (int i = tid; i < 32 * 256; i += 256) {
        int f = i >> 8, gg = i & 255;
        SFT[gg][f] = sf[((size_t)(b * 32 + f)) * 256 + gg];
    }
    __syncthreads();
    float acc[32];
#pragma unroll
    for (int f = 0; f < 32; f++) acc[f] = 0.f;
    for (int gg = 0; gg < 256; gg++) {
        float w = Wb[gg * 256 + tid];
#pragma unroll
        for (int f4 = 0; f4 < 8; f4++) {
            float4 x4 = ((const float4*)&SFT[gg][0])[f4];
            acc[f4 * 4 + 0] += w * x4.x;
            acc[f4 * 4 + 1] += w * x4.y;
            acc[f4 * 4 + 2] += w * x4.z;
            acc[f4 * 4 + 3] += w * x4.w;
        }
    }
#pragma unroll
    for (int f = 0; f < 32; f++)
        vout[((size_t)(b * 32 + f)) * 256 + tid] = acc[f];
}

// ---------------------------------------------------------------------------
// tf[n] = sum_s softplus(common_x[n,s,:]·v[n,:]) * exp(-time) * (s < clen)
// ---------------------------------------------------------------------------
__global__ __launch_bounds__(256)
void tf_kernel(const float* __restrict__ common_x, const float* __restrict__ common_time,
               const int* __restrict__ clen, const float* __restrict__ v,
               float* __restrict__ tf) {
    __shared__ float V[256];
    __shared__ float partial[4];
    int n = blockIdx.x, tid = threadIdx.x, wv = tid >> 6, lane = tid & 63;
    V[tid] = v[(size_t)n * 256 + tid];
    __syncthreads();
    float4 vv = ((const float4*)V)[lane];
    int cl = clen[n];
    float acc = 0.f;
    for (int s = wv; s < SS; s += 4) {
        float4 cx = ((const float4*)(common_x + ((size_t)n * SS + s) * HD))[lane];
        float d = cx.x * vv.x + cx.y * vv.y + cx.z * vv.z + cx.w * vv.w;
#pragma unroll
        for (int off = 32; off; off >>= 1) d += __shfl_xor(d, off);
        if (lane == 0 && s < cl) {
            float sp = (d > 20.f) ? d : log1pf(__expf(d));
            acc += sp * __expf(-common_time[n * SS + s]);
        }
    }
    if (lane == 0) partial[wv] = acc;
    __syncthreads();
    if (tid == 0) tf[n] = partial[0] + partial[1] + partial[2] + partial[3];
}

// ---------------------------------------------------------------------------
// softmax over padded MAXF (invalid logits are exactly 0) + weighted sum.
// ---------------------------------------------------------------------------
__global__ __launch_bounds__(256)
void out_kernel(const float* __restrict__ tf, const int* __restrict__ fnum,
                const float* __restrict__ fl, float* __restrict__ out) {
    __shared__ float e[32];
    __shared__ float tfm[32];
    __shared__ float Zs;
    int b = blockIdx.x, tid = threadIdx.x;
    int nv = fnum[b];
    if (tid < 32) tfm[tid] = (tid < nv) ? tf[b * 32 + tid] : 0.f;
    __syncthreads();
    if (tid == 0) {
        float m = tfm[0];
        for (int f = 1; f < 32; f++) m = fmaxf(m, tfm[f]);
        float Z = 0.f;
        for (int f = 0; f < 32; f++) { e[f] = __expf(tfm[f] - m); Z += e[f]; }
        Zs = Z;
    }
    __syncthreads();
    float Zi = 1.f / Zs;
    float o = 0.f;
    for (int f = 0; f < nv; f++)
        o += e[f] * Zi * fl[((size_t)(b * 32 + f)) * 256 + tid];
    out[b * 256 + tid] = o;
}

// ---------------------------------------------------------------------------
extern "C" void kernel_launch(void* const* d_in, const int* in_sizes, int n_in,
                              void* d_out, int out_size, void* d_ws, size_t ws_size,
                              hipStream_t stream) {
    (void)in_sizes; (void)n_in; (void)out_size; (void)ws_size;
    const float* self_x      = (const float*)d_in[0];
    const float* common_x    = (const float*)d_in[1];
    const float* common_time = (const float*)d_in[2];
    const float* friend_x    = (const float*)d_in[3];
    const float* Wih0 = (const float*)d_in[4];
    const float* Whh0 = (const float*)d_in[5];
    const float* bih0 = (const float*)d_in[6];
    const float* bhh0 = (const float*)d_in[7];
    const float* Wih1 = (const float*)d_in[8];
    const float* Whh1 = (const float*)d_in[9];
    const float* bih1 = (const float*)d_in[10];
    const float* bhh1 = (const float*)d_in[11];
    const float* Wf   = (const float*)d_in[12];
    const float* Wb   = (const float*)d_in[13];
    const int* flen   = (const int*)d_in[14];
    const int* fnum   = (const int*)d_in[15];
    const int* clen   = (const int*)d_in[16];
    float* out = (float*)d_out;

    char* ws = (char*)d_ws;
    unsigned short* wpk_hi = (unsigned short*)ws; ws += (size_t)786432 * 2;
    unsigned short* wpk_lo = (unsigned short*)ws; ws += (size_t)786432 * 2;
    float* WfT = (float*)ws;  ws += (size_t)512 * 256 * 4;
    int*   sid = (int*)ws;    ws += (size_t)2048 * 4;
    float* fl  = (float*)ws;  ws += (size_t)2048 * 256 * 4;
    float* sf  = (float*)ws;  ws += (size_t)2048 * 256 * 4;
    float* vv  = (float*)ws;  ws += (size_t)2048 * 256 * 4;
    float* tf  = (float*)ws;  ws += (size_t)2048 * 4;

    pack_kernel<<<3584, 256, 0, stream>>>(Wih0, Whh0, Wih1, Whh1, Wf, wpk_hi, wpk_lo, WfT);
    sort_kernel<<<1, 256, 0, stream>>>(flen, sid);
    gru_kernel<<<NBLK, 256, 0, stream>>>(friend_x, flen, sid, wpk_hi, wpk_lo,
                                         bih0, bhh0, bih1, bhh1, fl);
    sf_kernel<<<64, 256, 0, stream>>>(self_x, fl, WfT, sf);
    v_kernel<<<64, 256, 0, stream>>>(sf, Wb, vv);
    tf_kernel<<<2048, 256, 0, stream>>>(common_x, common_time, clen, vv, tf);
    out_kernel<<<64, 256, 0, stream>>>(tf, fnum, fl, out);
}

// Round 2
// 6412.084 us; speedup vs baseline: 2.1069x; 2.1069x over previous
//
#include <hip/hip_runtime.h>
#include <hip/hip_bf16.h>
#include <stdint.h>

// Problem constants
#define HD    256      // hidden
#define LL    50       // friend seq len
#define SS    50       // common seq len
#define NB    64       // batch
#define MAXF  32
#define NSEQ  2048     // NB*MAXF
#define MB    16       // sequences per block (one 16-row MFMA M-tile)
#define NBLK  128      // NSEQ/MB
#define XP    280      // padded LDS row (bf16 elems): 560B rows, 16B-aligned, bank stride 12

typedef __attribute__((ext_vector_type(8))) short bf16x8;
typedef __attribute__((ext_vector_type(4))) float f32x4;
typedef __attribute__((ext_vector_type(4))) unsigned short u16x4;

__device__ __forceinline__ f32x4 mfma16(bf16x8 a, bf16x8 b, f32x4 c) {
    return __builtin_amdgcn_mfma_f32_16x16x32_bf16(a, b, c, 0, 0, 0);
}

__device__ __forceinline__ unsigned short f2bf_rne(float f) {
    union { float f; uint32_t u; } v; v.f = f;
    uint32_t u = v.u;
    uint32_t r = u + 0x7FFFu + ((u >> 16) & 1u);
    return (unsigned short)(r >> 16);
}
__device__ __forceinline__ float bf2f(unsigned short b) {
    union { float f; uint32_t u; } v; v.u = ((uint32_t)b) << 16;
    return v.f;
}

// ---------------------------------------------------------------------------
// Pack: weights -> fused hi/lo bf16 planes in MFMA fragment order + Wf^T.
// wpk layout: [l(2)][m(2: ih,hh)][nt(48)][c(8)][plane(2: hi,lo)][lane(64)][j(8)]
// fragment semantics: gate row n = nt*16 + (lane&15), k = c*32 + (lane>>4)*8 + j
// ---------------------------------------------------------------------------
__global__ void pack_kernel(const float* __restrict__ Wih0, const float* __restrict__ Whh0,
                            const float* __restrict__ Wih1, const float* __restrict__ Whh1,
                            const float* __restrict__ Wf,
                            unsigned short* __restrict__ wpk,
                            float* __restrict__ WfT) {
    int idx = blockIdx.x * blockDim.x + threadIdx.x;
    const int TOTW = 2 * 2 * 48 * 8 * 2 * 64 * 8;   // 1572864
    if (idx < TOTW) {
        int j     = idx & 7;
        int lane  = (idx >> 3) & 63;
        int plane = (idx >> 9) & 1;
        int c     = (idx >> 10) & 7;
        int ntlm  = idx >> 13;
        int nt    = ntlm % 48;
        int lm    = ntlm / 48;                       // 0..3 : Wih0,Whh0,Wih1,Whh1
        const float* W = (lm == 0) ? Wih0 : (lm == 1) ? Whh0 : (lm == 2) ? Wih1 : Whh1;
        int n = nt * 16 + (lane & 15);
        int k = c * 32 + (lane >> 4) * 8 + j;
        float v = W[n * HD + k];
        unsigned short hi = f2bf_rne(v);
        wpk[idx] = plane ? f2bf_rne(v - bf2f(hi)) : hi;
    } else {
        int idx2 = idx - TOTW;
        if (idx2 < 512 * 256) {                      // WfT[k][h] = Wf[h][k]
            int k = idx2 >> 8; int h = idx2 & 255;
            WfT[k * 256 + h] = Wf[h * 512 + k];
        }
    }
}

// ---------------------------------------------------------------------------
// Counting sort of the 2048 sequences by friend_len (1..50), ascending.
// ---------------------------------------------------------------------------
__global__ void sort_kernel(const int* __restrict__ flen, int* __restrict__ sid) {
    __shared__ int hist[64];
    __shared__ int offs[64];
    int tid = threadIdx.x;
    if (tid < 64) hist[tid] = 0;
    __syncthreads();
    for (int i = tid; i < NSEQ; i += blockDim.x) atomicAdd(&hist[flen[i]], 1);
    __syncthreads();
    if (tid == 0) {
        int acc = 0;
        for (int v = 1; v <= 50; v++) { offs[v] = acc; acc += hist[v]; }
    }
    __syncthreads();
    for (int i = tid; i < NSEQ; i += blockDim.x) {
        int pos = atomicAdd(&offs[flen[i]], 1);
        sid[pos] = i;
    }
}

// ---------------------------------------------------------------------------
// Fused 2-layer GRU. 1024 threads = 16 waves; wave w owns gate tiles
// {w, 16+w, 32+w} -> gate columns j in [16w, 16w+16). 96 weight loads per
// wave per layer-step (was 384 @ 4 waves), triple-buffered group prefetch.
// Split-bf16 (hi+lo) 3-term MFMA throughout.
// ---------------------------------------------------------------------------
__global__ __launch_bounds__(1024)
void gru_kernel(const float* __restrict__ friend_x,
                const int* __restrict__ flen,
                const int* __restrict__ sid,
                const unsigned short* __restrict__ wpk,
                const float* __restrict__ bih0, const float* __restrict__ bhh0,
                const float* __restrict__ bih1, const float* __restrict__ bhh1,
                float* __restrict__ friend_last) {
    __shared__ unsigned short Xhi[MB][XP],  Xlo[MB][XP];
    __shared__ unsigned short H0hi[MB][XP], H0lo[MB][XP];
    __shared__ unsigned short H1hi[MB][XP], H1lo[MB][XP];
    __shared__ int sidS[MB], lenS[MB];

    const int tid  = threadIdx.x;
    const int g    = blockIdx.x;
    const int wv   = tid >> 6;     // 0..15
    const int lane = tid & 63;

    if (tid < MB) {
        int s_ = sid[g * MB + tid];
        sidS[tid] = s_;
        lenS[tid] = flen[s_];
    }
    for (int i = tid; i < MB * XP; i += 1024) {
        (&H0hi[0][0])[i] = 0; (&H0lo[0][0])[i] = 0;
        (&H1hi[0][0])[i] = 0; (&H1lo[0][0])[i] = 0;
    }
    __syncthreads();

    int maxlen = 0;
#pragma unroll
    for (int s = 0; s < MB; s++) maxlen = max(maxlen, lenS[s]);

    const int qrow = (lane >> 4) * 4;     // acc rows = sequences qrow..qrow+3
    const int cn   = lane & 15;
    const int j    = wv * 16 + cn;        // this lane's gate column

    // biases for column j
    const float b0R  = bih0[j]       + bhh0[j];
    const float b0Z  = bih0[256 + j] + bhh0[256 + j];
    const float b0NI = bih0[512 + j];
    const float b0NH = bhh0[512 + j];
    const float b1R  = bih1[j]       + bhh1[j];
    const float b1Z  = bih1[256 + j] + bhh1[256 + j];
    const float b1NI = bih1[512 + j];
    const float b1NH = bhh1[512 + j];

    int lenR[4], sidR[4];
#pragma unroll
    for (int r = 0; r < 4; r++) { lenR[r] = lenS[qrow + r]; sidR[r] = sidS[qrow + r]; }

    float h0reg[4] = {0.f, 0.f, 0.f, 0.f};
    float h1reg[4] = {0.f, 0.f, 0.f, 0.f};

    // wave w stages sequence w's x(t): 64 lanes x float4 = 256 cols
    auto stageX = [&](int t) {
        float4 f4 = ((const float4*)(friend_x + ((size_t)sidS[wv] * LL + t) * HD))[lane];
        float vals[4] = { f4.x, f4.y, f4.z, f4.w };
        u16x4 hi4, lo4;
#pragma unroll
        for (int e = 0; e < 4; e++) {
            unsigned short hi_ = f2bf_rne(vals[e]);
            hi4[e] = hi_;
            lo4[e] = f2bf_rne(vals[e] - bf2f(hi_));
        }
        *(u16x4*)&Xhi[wv][lane * 4] = hi4;
        *(u16x4*)&Xlo[wv][lane * 4] = lo4;
    };

    auto loadFrag = [&](const unsigned short (*A)[XP], int c) -> bf16x8 {
        return *(const bf16x8*)&A[lane & 15][c * 32 + (lane >> 4) * 8];
    };

    // weight base for this wave: nt = wv + 16*t3
    const unsigned short* pw = wpk + wv * 8192 + lane * 8;
    auto loadGroup = [&](bf16x8* B, int l, int m, int c) {
        const unsigned short* p = pw + (l * 2 + m) * 393216 + c * 1024;
#pragma unroll
        for (int t3 = 0; t3 < 3; t3++) {
            B[t3 * 2 + 0] = *(const bf16x8*)(p + t3 * 131072);        // hi
            B[t3 * 2 + 1] = *(const bf16x8*)(p + t3 * 131072 + 512);  // lo
        }
    };

    bf16x8 Ih[8], Il[8], Hh[8], Hl[8];   // A-fragments (input / hidden), hi+lo

    auto doLayer = [&](int l, float* hreg,
                       float cbR, float cbZ, float cbNI, float cbNH,
                       unsigned short (*Ohi)[XP], unsigned short (*Olo)[XP],
                       bool gather, int t) {
        f32x4 aR  = {0.f, 0.f, 0.f, 0.f};
        f32x4 aZ  = {0.f, 0.f, 0.f, 0.f};
        f32x4 aNi = {0.f, 0.f, 0.f, 0.f};
        f32x4 aNh = {0.f, 0.f, 0.f, 0.f};

        bf16x8 Bb[3][6];
        loadGroup(Bb[0], l, 0, 0);
        loadGroup(Bb[1], l, 0, 1);
#pragma unroll
        for (int gg = 0; gg < 16; gg++) {
            const int m = gg >> 3, c = gg & 7;
            if (gg + 2 < 16) {
                const int g2 = gg + 2;
                loadGroup(Bb[g2 % 3], l, g2 >> 3, g2 & 7);
            }
            const bf16x8* B = Bb[gg % 3];
            bf16x8 ah = m ? Hh[c] : Ih[c];
            bf16x8 al = m ? Hl[c] : Il[c];
            f32x4& aN = m ? aNh : aNi;
            aR = mfma16(ah, B[0], aR);
            aR = mfma16(al, B[0], aR);
            aR = mfma16(ah, B[1], aR);
            aZ = mfma16(ah, B[2], aZ);
            aZ = mfma16(al, B[2], aZ);
            aZ = mfma16(ah, B[3], aZ);
            aN = mfma16(ah, B[4], aN);
            aN = mfma16(al, B[4], aN);
            aN = mfma16(ah, B[5], aN);
        }
        // gates: C-layout row = qrow + r (sequence), col = cn -> column j
#pragma unroll
        for (int r = 0; r < 4; r++) {
            float pre_r = aR[r]  + cbR;
            float pre_z = aZ[r]  + cbZ;
            float gin   = aNi[r] + cbNI;
            float ghn   = aNh[r] + cbNH;
            float rr = 1.f / (1.f + __expf(-pre_r));
            float zz = 1.f / (1.f + __expf(-pre_z));
            float nx = gin + rr * ghn;
            float e  = __expf(-2.f * fabsf(nx));
            float th = 1.f - 2.f * e / (1.f + e);
            th = (nx < 0.f) ? -th : th;
            float hNew = (1.f - zz) * th + zz * hreg[r];
            hreg[r] = hNew;
            int s = qrow + r;
            unsigned short hi_ = f2bf_rne(hNew);
            Ohi[s][j] = hi_;
            Olo[s][j] = f2bf_rne(hNew - bf2f(hi_));
            if (gather && t == lenR[r] - 1)
                friend_last[(size_t)sidR[r] * HD + j] = hNew;
        }
    };

    stageX(0);
    __syncthreads();

    for (int t = 0; t < maxlen; t++) {
        // Layer 0 fragments: A = x(t), hidden = h0(t-1)
#pragma unroll
        for (int c = 0; c < 8; c++) {
            Ih[c] = loadFrag(Xhi, c);  Il[c] = loadFrag(Xlo, c);
            Hh[c] = loadFrag(H0hi, c); Hl[c] = loadFrag(H0lo, c);
        }
        __syncthreads();                     // X / H0 now writable
        if (t + 1 < maxlen) stageX(t + 1);   // overlap next-step staging
        doLayer(0, h0reg, b0R, b0Z, b0NI, b0NH, H0hi, H0lo, false, t);
        __syncthreads();                     // h0(t) visible
        // Layer 1 fragments: A = h0(t), hidden = h1(t-1)
#pragma unroll
        for (int c = 0; c < 8; c++) {
            Ih[c] = loadFrag(H0hi, c); Il[c] = loadFrag(H0lo, c);
            Hh[c] = loadFrag(H1hi, c); Hl[c] = loadFrag(H1lo, c);
        }
        __syncthreads();                     // H1 writable
        doLayer(1, h1reg, b1R, b1Z, b1NI, b1NH, H1hi, H1lo, true, t);
        __syncthreads();                     // h1(t) visible
    }
}

// ---------------------------------------------------------------------------
// sf[n,h] = Wf[h,:256]·self_x[b] + Wf[h,256:]·friend_last[n]   (fp32 exact)
// ---------------------------------------------------------------------------
__global__ __launch_bounds__(256)
void sf_kernel(const float* __restrict__ self_x, const float* __restrict__ fl,
               const float* __restrict__ WfT, float* __restrict__ sf) {
    __shared__ float S[256];
    __shared__ float FLT[256][36];   // [k][f], padded
    int b = blockIdx.x, tid = threadIdx.x;
    S[tid] = self_x[b * 256 + tid];
    for (int i = tid; i < 32 * 256; i += 256) {
        int f = i >> 8, k = i & 255;
        FLT[k][f] = fl[((size_t)(b * 32 + f)) * 256 + k];
    }
    __syncthreads();
    float acc0 = 0.f;
    for (int k = 0; k < 256; k++) acc0 += WfT[k * 256 + tid] * S[k];
    float acc[32];
#pragma unroll
    for (int f = 0; f < 32; f++) acc[f] = acc0;
    for (int k = 0; k < 256; k++) {
        float w = WfT[(256 + k) * 256 + tid];
#pragma unroll
        for (int f4 = 0; f4 < 8; f4++) {
            float4 x4 = ((const float4*)&FLT[k][0])[f4];
            acc[f4 * 4 + 0] += w * x4.x;
            acc[f4 * 4 + 1] += w * x4.y;
            acc[f4 * 4 + 2] += w * x4.z;
            acc[f4 * 4 + 3] += w * x4.w;
        }
    }
#pragma unroll
    for (int f = 0; f < 32; f++)
        sf[((size_t)(b * 32 + f)) * 256 + tid] = acc[f];
}

// ---------------------------------------------------------------------------
// v[n,h] = sum_g Wb[g,h] * sf[n,g]
// ---------------------------------------------------------------------------
__global__ __launch_bounds__(256)
void v_kernel(const float* __restrict__ sf, const float* __restrict__ Wb,
              float* __restrict__ vout) {
    __shared__ float SFT[256][36];   // [g][f]
    int b = blockIdx.x, tid = threadIdx.x;
    for (int i = tid; i < 32 * 256; i += 256) {
        int f = i >> 8, gg = i & 255;
        SFT[gg][f] = sf[((size_t)(b * 32 + f)) * 256 + gg];
    }
    __syncthreads();
    float acc[32];
#pragma unroll
    for (int f = 0; f < 32; f++) acc[f] = 0.f;
    for (int gg = 0; gg < 256; gg++) {
        float w = Wb[gg * 256 + tid];
#pragma unroll
        for (int f4 = 0; f4 < 8; f4++) {
            float4 x4 = ((const float4*)&SFT[gg][0])[f4];
            acc[f4 * 4 + 0] += w * x4.x;
            acc[f4 * 4 + 1] += w * x4.y;
            acc[f4 * 4 + 2] += w * x4.z;
            acc[f4 * 4 + 3] += w * x4.w;
        }
    }
#pragma unroll
    for (int f = 0; f < 32; f++)
        vout[((size_t)(b * 32 + f)) * 256 + tid] = acc[f];
}

// ---------------------------------------------------------------------------
// tf[n] = sum_s softplus(common_x[n,s,:]·v[n,:]) * exp(-time) * (s < clen)
// ---------------------------------------------------------------------------
__global__ __launch_bounds__(256)
void tf_kernel(const float* __restrict__ common_x, const float* __restrict__ common_time,
               const int* __restrict__ clen, const float* __restrict__ v,
               float* __restrict__ tf) {
    __shared__ float V[256];
    __shared__ float partial[4];
    int n = blockIdx.x, tid = threadIdx.x, wv = tid >> 6, lane = tid & 63;
    V[tid] = v[(size_t)n * 256 + tid];
    __syncthreads();
    float4 vv = ((const float4*)V)[lane];
    int cl = clen[n];
    float acc = 0.f;
    for (int s = wv; s < SS; s += 4) {
        float4 cx = ((const float4*)(common_x + ((size_t)n * SS + s) * HD))[lane];
        float d = cx.x * vv.x + cx.y * vv.y + cx.z * vv.z + cx.w * vv.w;
#pragma unroll
        for (int off = 32; off; off >>= 1) d += __shfl_xor(d, off);
        if (lane == 0 && s < cl) {
            float sp = (d > 20.f) ? d : log1pf(__expf(d));
            acc += sp * __expf(-common_time[n * SS + s]);
        }
    }
    if (lane == 0) partial[wv] = acc;
    __syncthreads();
    if (tid == 0) tf[n] = partial[0] + partial[1] + partial[2] + partial[3];
}

// ---------------------------------------------------------------------------
// softmax over padded MAXF (invalid logits are exactly 0) + weighted sum.
// ---------------------------------------------------------------------------
__global__ __launch_bounds__(256)
void out_kernel(const float* __restrict__ tf, const int* __restrict__ fnum,
                const float* __restrict__ fl, float* __restrict__ out) {
    __shared__ float e[32];
    __shared__ float tfm[32];
    __shared__ float Zs;
    int b = blockIdx.x, tid = threadIdx.x;
    int nv = fnum[b];
    if (tid < 32) tfm[tid] = (tid < nv) ? tf[b * 32 + tid] : 0.f;
    __syncthreads();
    if (tid == 0) {
        float m = tfm[0];
        for (int f = 1; f < 32; f++) m = fmaxf(m, tfm[f]);
        float Z = 0.f;
        for (int f = 0; f < 32; f++) { e[f] = __expf(tfm[f] - m); Z += e[f]; }
        Zs = Z;
    }
    __syncthreads();
    float Zi = 1.f / Zs;
    float o = 0.f;
    for (int f = 0; f < nv; f++)
        o += e[f] * Zi * fl[((size_t)(b * 32 + f)) * 256 + tid];
    out[b * 256 + tid] = o;
}

// ---------------------------------------------------------------------------
extern "C" void kernel_launch(void* const* d_in, const int* in_sizes, int n_in,
                              void* d_out, int out_size, void* d_ws, size_t ws_size,
                              hipStream_t stream) {
    (void)in_sizes; (void)n_in; (void)out_size; (void)ws_size;
    const float* self_x      = (const float*)d_in[0];
    const float* common_x    = (const float*)d_in[1];
    const float* common_time = (const float*)d_in[2];
    const float* friend_x    = (const float*)d_in[3];
    const float* Wih0 = (const float*)d_in[4];
    const float* Whh0 = (const float*)d_in[5];
    const float* bih0 = (const float*)d_in[6];
    const float* bhh0 = (const float*)d_in[7];
    const float* Wih1 = (const float*)d_in[8];
    const float* Whh1 = (const float*)d_in[9];
    const float* bih1 = (const float*)d_in[10];
    const float* bhh1 = (const float*)d_in[11];
    const float* Wf   = (const float*)d_in[12];
    const float* Wb   = (const float*)d_in[13];
    const int* flen   = (const int*)d_in[14];
    const int* fnum   = (const int*)d_in[15];
    const int* clen   = (const int*)d_in[16];
    float* out = (float*)d_out;

    char* ws = (char*)d_ws;
    unsigned short* wpk = (unsigned short*)ws; ws += (size_t)1572864 * 2;
    float* WfT = (float*)ws;  ws += (size_t)512 * 256 * 4;
    int*   sid = (int*)ws;    ws += (size_t)2048 * 4;
    float* fl  = (float*)ws;  ws += (size_t)2048 * 256 * 4;
    float* sf  = (float*)ws;  ws += (size_t)2048 * 256 * 4;
    float* vv  = (float*)ws;  ws += (size_t)2048 * 256 * 4;
    float* tf  = (float*)ws;  ws += (size_t)2048 * 4;

    pack_kernel<<<6656, 256, 0, stream>>>(Wih0, Whh0, Wih1, Whh1, Wf, wpk, WfT);
    sort_kernel<<<1, 256, 0, stream>>>(flen, sid);
    gru_kernel<<<NBLK, 1024, 0, stream>>>(friend_x, flen, sid, wpk,
                                          bih0, bhh0, bih1, bhh1, fl);
    sf_kernel<<<64, 256, 0, stream>>>(self_x, fl, WfT, sf);
    v_kernel<<<64, 256, 0, stream>>>(sf, Wb, vv);
    tf_kernel<<<2048, 256, 0, stream>>>(common_x, common_time, clen, vv, tf);
    out_kernel<<<64, 256, 0, stream>>>(tf, fnum, fl, out);
}

// Round 3
// 5289.973 us; speedup vs baseline: 2.5538x; 1.2121x over previous
//
#include <hip/hip_runtime.h>
#include <hip/hip_bf16.h>
#include <stdint.h>

// Problem constants
#define HD    256      // hidden
#define LL    50       // friend seq len
#define SS    50       // common seq len
#define NB    64       // batch
#define MAXF  32
#define NSEQ  2048     // NB*MAXF
#define MB    16       // sequences per block (one 16-row MFMA M-tile)
#define NBLK  128      // NSEQ/MB
#define XP    264      // padded LDS row (bf16): 528B rows -> bank stride 4 mod 32, 2-way max (free)

typedef __attribute__((ext_vector_type(8))) short bf16x8;
typedef __attribute__((ext_vector_type(4))) float f32x4;
typedef __attribute__((ext_vector_type(4))) unsigned short u16x4;

__device__ __forceinline__ f32x4 mfma16(bf16x8 a, bf16x8 b, f32x4 c) {
    return __builtin_amdgcn_mfma_f32_16x16x32_bf16(a, b, c, 0, 0, 0);
}

__device__ __forceinline__ unsigned short f2bf_rne(float f) {
    union { float f; uint32_t u; } v; v.f = f;
    uint32_t u = v.u;
    uint32_t r = u + 0x7FFFu + ((u >> 16) & 1u);
    return (unsigned short)(r >> 16);
}
__device__ __forceinline__ float bf2f(unsigned short b) {
    union { float f; uint32_t u; } v; v.u = ((uint32_t)b) << 16;
    return v.f;
}

// ---------------------------------------------------------------------------
// Pack weights -> per-wave-contiguous MFMA fragment slices + Wf^T.
// wpk layout: [wv(16)][lm(4: l*2+m)][c(8)][t3(3)][plane(2: hi,lo)][lane(64)][j(8)]
//   gate tile nt = wv + 16*t3; row n = nt*16 + (lane&15); k = c*32 + (lane>>4)*8 + j
// One (l,m,c) "group" for a wave = 6 contiguous 1KB fragments (6144 B).
// ---------------------------------------------------------------------------
__global__ void pack_kernel(const float* __restrict__ Wih0, const float* __restrict__ Whh0,
                            const float* __restrict__ Wih1, const float* __restrict__ Whh1,
                            const float* __restrict__ Wf,
                            unsigned short* __restrict__ wpk,
                            float* __restrict__ WfT) {
    int idx = blockIdx.x * blockDim.x + threadIdx.x;
    const int TOTW = 16 * 4 * 8 * 3 * 2 * 64 * 8;   // 1572864
    if (idx < TOTW) {
        int j     = idx & 7;
        int lane  = (idx >> 3) & 63;
        int plane = (idx >> 9) & 1;
        int rest  = idx >> 10;
        int t3    = rest % 3;
        int rest2 = rest / 3;
        int c     = rest2 & 7;
        int lm    = (rest2 >> 3) & 3;                // l*2+m: Wih0,Whh0,Wih1,Whh1
        int wvv   = rest2 >> 5;
        const float* W = (lm == 0) ? Wih0 : (lm == 1) ? Whh0 : (lm == 2) ? Wih1 : Whh1;
        int nt = wvv + 16 * t3;
        int n  = nt * 16 + (lane & 15);
        int k  = c * 32 + (lane >> 4) * 8 + j;
        float v = W[n * HD + k];
        unsigned short hi = f2bf_rne(v);
        wpk[idx] = plane ? f2bf_rne(v - bf2f(hi)) : hi;
    } else {
        int idx2 = idx - TOTW;
        if (idx2 < 512 * 256) {                      // WfT[k][h] = Wf[h][k]
            int k = idx2 >> 8; int h = idx2 & 255;
            WfT[k * 256 + h] = Wf[h * 512 + k];
        }
    }
}

// ---------------------------------------------------------------------------
// Counting sort of the 2048 sequences by friend_len (1..50), ascending.
// ---------------------------------------------------------------------------
__global__ void sort_kernel(const int* __restrict__ flen, int* __restrict__ sid) {
    __shared__ int hist[64];
    __shared__ int offs[64];
    int tid = threadIdx.x;
    if (tid < 64) hist[tid] = 0;
    __syncthreads();
    for (int i = tid; i < NSEQ; i += blockDim.x) atomicAdd(&hist[flen[i]], 1);
    __syncthreads();
    if (tid == 0) {
        int acc = 0;
        for (int v = 1; v <= 50; v++) { offs[v] = acc; acc += hist[v]; }
    }
    __syncthreads();
    for (int i = tid; i < NSEQ; i += blockDim.x) {
        int pos = atomicAdd(&offs[flen[i]], 1);
        sid[pos] = i;
    }
}

// ---------------------------------------------------------------------------
// Fused 2-layer GRU. 1024 threads = 16 waves, 1 block/CU, <=128 VGPR (no spill).
// Wave w owns gate tiles {w, 16+w, 32+w} -> columns [16w,16w+16).
// A-fragments read on-demand from LDS; single-buffered X/H0/H1; 3 barriers/step.
// Split-bf16 (hi+lo) 3-term MFMA throughout (~2^-16 effective precision).
// ---------------------------------------------------------------------------
__global__ __launch_bounds__(1024, 4)
void gru_kernel(const float* __restrict__ friend_x,
                const int* __restrict__ flen,
                const int* __restrict__ sid,
                const unsigned short* __restrict__ wpk,
                const float* __restrict__ bih0, const float* __restrict__ bhh0,
                const float* __restrict__ bih1, const float* __restrict__ bhh1,
                float* __restrict__ friend_last) {
    __shared__ unsigned short Xhi[MB][XP],  Xlo[MB][XP];
    __shared__ unsigned short H0hi[MB][XP], H0lo[MB][XP];
    __shared__ unsigned short H1hi[MB][XP], H1lo[MB][XP];
    __shared__ int sidS[MB], lenS[MB];

    const int tid  = threadIdx.x;
    const int g    = blockIdx.x;
    const int wv   = __builtin_amdgcn_readfirstlane(tid >> 6);   // wave-uniform
    const int lane = tid & 63;
    const int mrow = lane & 15;          // A-frag row / C col-within-tile
    const int quad = lane >> 4;

    if (tid < MB) {
        int s_ = sid[g * MB + tid];
        sidS[tid] = s_;
        lenS[tid] = flen[s_];
    }
    for (int i = tid; i < MB * XP; i += 1024) {
        (&H0hi[0][0])[i] = 0; (&H0lo[0][0])[i] = 0;
        (&H1hi[0][0])[i] = 0; (&H1lo[0][0])[i] = 0;
    }
    __syncthreads();

    int maxlen = 0;
#pragma unroll
    for (int s = 0; s < MB; s++) maxlen = max(maxlen, lenS[s]);

    const int qrow = quad * 4;           // C-layout rows (sequences) qrow..qrow+3
    const int j    = wv * 16 + mrow;     // this lane's gate column

    const float b0R  = bih0[j]       + bhh0[j];
    const float b0Z  = bih0[256 + j] + bhh0[256 + j];
    const float b0NI = bih0[512 + j];
    const float b0NH = bhh0[512 + j];
    const float b1R  = bih1[j]       + bhh1[j];
    const float b1Z  = bih1[256 + j] + bhh1[256 + j];
    const float b1NI = bih1[512 + j];
    const float b1NH = bhh1[512 + j];

    int lenR[4], sidR[4];
#pragma unroll
    for (int r = 0; r < 4; r++) { lenR[r] = lenS[qrow + r]; sidR[r] = sidS[qrow + r]; }

    float h0reg[4] = {0.f, 0.f, 0.f, 0.f};
    float h1reg[4] = {0.f, 0.f, 0.f, 0.f};

    // per-wave contiguous weight base
    const unsigned short* pw = wpk + (size_t)wv * 98304 + (size_t)lane * 8;

    auto loadGroup = [&](bf16x8* B, int lm, int c) {
        const unsigned short* p = pw + (size_t)(lm * 8 + c) * 3072;
        B[0] = *(const bf16x8*)(p);            // t3=0 hi (r-gate)
        B[1] = *(const bf16x8*)(p + 512);      // t3=0 lo
        B[2] = *(const bf16x8*)(p + 1024);     // t3=1 hi (z-gate)
        B[3] = *(const bf16x8*)(p + 1536);
        B[4] = *(const bf16x8*)(p + 2048);     // t3=2 hi (n-gate)
        B[5] = *(const bf16x8*)(p + 2560);
    };
    const int fragOff = (lane & 15) * XP + quad * 8;   // + c*32 elems

    // MFMA phase of one layer: input A-arrays (Ih,Il), hidden A-arrays (Hh,Hl)
    auto layerMM = [&](int l,
                       const unsigned short* Ih, const unsigned short* Il,
                       const unsigned short* Hh, const unsigned short* Hl,
                       f32x4& aR, f32x4& aZ, f32x4& aNi, f32x4& aNh) {
        bf16x8 Bb[2][6];
        loadGroup(Bb[0], l * 2, 0);
#pragma unroll
        for (int gg = 0; gg < 16; gg++) {
            const int m = gg >> 3, c = gg & 7;
            if (gg + 1 < 16) loadGroup(Bb[(gg + 1) & 1], l * 2 + ((gg + 1) >> 3), (gg + 1) & 7);
            bf16x8 ah = *(const bf16x8*)((m ? Hh : Ih) + fragOff + c * 32);
            bf16x8 al = *(const bf16x8*)((m ? Hl : Il) + fragOff + c * 32);
            const bf16x8* B = Bb[gg & 1];
            f32x4& aN = m ? aNh : aNi;
            aR = mfma16(ah, B[0], aR);
            aR = mfma16(al, B[0], aR);
            aR = mfma16(ah, B[1], aR);
            aZ = mfma16(ah, B[2], aZ);
            aZ = mfma16(al, B[2], aZ);
            aZ = mfma16(ah, B[3], aZ);
            aN = mfma16(ah, B[4], aN);
            aN = mfma16(al, B[4], aN);
            aN = mfma16(ah, B[5], aN);
        }
    };

    // gate epilogue: writes h(t) to LDS (call AFTER a barrier)
    auto epi = [&](f32x4 aR, f32x4 aZ, f32x4 aNi, f32x4 aNh, float* hreg,
                   float cbR, float cbZ, float cbNI, float cbNH,
                   unsigned short (*Ohi)[XP], unsigned short (*Olo)[XP],
                   bool gather, int t) {
#pragma unroll
        for (int r = 0; r < 4; r++) {
            float pre_r = aR[r]  + cbR;
            float pre_z = aZ[r]  + cbZ;
            float gin   = aNi[r] + cbNI;
            float ghn   = aNh[r] + cbNH;
            float rr = 1.f / (1.f + __expf(-pre_r));
            float zz = 1.f / (1.f + __expf(-pre_z));
            float nx = gin + rr * ghn;
            float e  = __expf(-2.f * fabsf(nx));
            float th = 1.f - 2.f * e / (1.f + e);
            th = (nx < 0.f) ? -th : th;
            float hNew = (1.f - zz) * th + zz * hreg[r];
            hreg[r] = hNew;
            int s = qrow + r;
            unsigned short hi_ = f2bf_rne(hNew);
            Ohi[s][j] = hi_;
            Olo[s][j] = f2bf_rne(hNew - bf2f(hi_));
            if (gather && t == lenR[r] - 1)
                friend_last[(size_t)sidR[r] * HD + j] = hNew;
        }
    };

    // stage x(0): wave w stages sequence w (64 lanes x float4 = 256 cols)
    {
        float4 f4 = ((const float4*)(friend_x + ((size_t)sidS[wv] * LL) * HD))[lane];
        float vals[4] = { f4.x, f4.y, f4.z, f4.w };
        u16x4 hi4, lo4;
#pragma unroll
        for (int e = 0; e < 4; e++) {
            unsigned short h_ = f2bf_rne(vals[e]);
            hi4[e] = h_;
            lo4[e] = f2bf_rne(vals[e] - bf2f(h_));
        }
        *(u16x4*)&Xhi[wv][lane * 4] = hi4;
        *(u16x4*)&Xlo[wv][lane * 4] = lo4;
    }
    __syncthreads();

    for (int t = 0; t < maxlen; t++) {
        // issue next-step staging load early (held in regs until after B1)
        int tn = (t + 1 < maxlen) ? t + 1 : t;
        float4 sx = ((const float4*)(friend_x + ((size_t)sidS[wv] * LL + tn) * HD))[lane];

        // ---- Layer 0 MFMAs: A = [x(t)], hidden = h0(t-1) ----
        f32x4 aR  = {0.f,0.f,0.f,0.f}, aZ = {0.f,0.f,0.f,0.f};
        f32x4 aNi = {0.f,0.f,0.f,0.f}, aNh = {0.f,0.f,0.f,0.f};
        layerMM(0, &Xhi[0][0], &Xlo[0][0], &H0hi[0][0], &H0lo[0][0], aR, aZ, aNi, aNh);
        __syncthreads();   // B1: all X / H0 reads complete
        epi(aR, aZ, aNi, aNh, h0reg, b0R, b0Z, b0NI, b0NH, H0hi, H0lo, false, t);
        {   // write x(t+1)
            float vals[4] = { sx.x, sx.y, sx.z, sx.w };
            u16x4 hi4, lo4;
#pragma unroll
            for (int e = 0; e < 4; e++) {
                unsigned short h_ = f2bf_rne(vals[e]);
                hi4[e] = h_;
                lo4[e] = f2bf_rne(vals[e] - bf2f(h_));
            }
            *(u16x4*)&Xhi[wv][lane * 4] = hi4;
            *(u16x4*)&Xlo[wv][lane * 4] = lo4;
        }
        __syncthreads();   // B2: h0(t) + x(t+1) visible
        // ---- Layer 1 MFMAs: A = [h0(t)], hidden = h1(t-1) ----
        aR = {0.f,0.f,0.f,0.f}; aZ = {0.f,0.f,0.f,0.f};
        aNi = {0.f,0.f,0.f,0.f}; aNh = {0.f,0.f,0.f,0.f};
        layerMM(1, &H0hi[0][0], &H0lo[0][0], &H1hi[0][0], &H1lo[0][0], aR, aZ, aNi, aNh);
        __syncthreads();   // B3: all H0 / H1 reads complete
        epi(aR, aZ, aNi, aNh, h1reg, b1R, b1Z, b1NI, b1NH, H1hi, H1lo, true, t);
        // epi writes -> next reads are separated by B1/B2 of the next iteration
    }
}

// ---------------------------------------------------------------------------
// Fused: sf[n,h] = Wf[h,:256]·self_x[b] + Wf[h,256:]·fl[n]; v[n,h] = Wb[:,h]·sf[n,:]
// ---------------------------------------------------------------------------
__global__ __launch_bounds__(256)
void sfv_kernel(const float* __restrict__ self_x, const float* __restrict__ fl,
                const float* __restrict__ WfT, const float* __restrict__ Wb,
                float* __restrict__ vout) {
    __shared__ float S[256];
    __shared__ float T[256][33];   // phase1: fl^T [k][f]; phase2: sf^T [g][f]
    int b = blockIdx.x, tid = threadIdx.x;
    S[tid] = self_x[b * 256 + tid];
    for (int i = tid; i < 32 * 256; i += 256) {
        int f = i >> 8, k = i & 255;
        T[k][f] = fl[((size_t)(b * 32 + f)) * 256 + k];
    }
    __syncthreads();
    float acc0 = 0.f;
    for (int k = 0; k < 256; k++) acc0 += WfT[k * 256 + tid] * S[k];
    float acc[32];
#pragma unroll
    for (int f = 0; f < 32; f++) acc[f] = acc0;
    for (int k = 0; k < 256; k++) {
        float w = WfT[(256 + k) * 256 + tid];
#pragma unroll
        for (int f = 0; f < 32; f++) acc[f] += w * T[k][f];
    }
    __syncthreads();
#pragma unroll
    for (int f = 0; f < 32; f++) T[tid][f] = acc[f];   // sf^T into LDS
    __syncthreads();
    float av[32];
#pragma unroll
    for (int f = 0; f < 32; f++) av[f] = 0.f;
    for (int gg = 0; gg < 256; gg++) {
        float w = Wb[gg * 256 + tid];
#pragma unroll
        for (int f = 0; f < 32; f++) av[f] += w * T[gg][f];
    }
#pragma unroll
    for (int f = 0; f < 32; f++)
        vout[((size_t)(b * 32 + f)) * 256 + tid] = av[f];
}

// ---------------------------------------------------------------------------
// tf[n] = sum_s softplus(common_x[n,s,:]·v[n,:]) * exp(-time) * (s < clen)
// ---------------------------------------------------------------------------
__global__ __launch_bounds__(256)
void tf_kernel(const float* __restrict__ common_x, const float* __restrict__ common_time,
               const int* __restrict__ clen, const float* __restrict__ v,
               float* __restrict__ tf) {
    __shared__ float V[256];
    __shared__ float partial[4];
    int n = blockIdx.x, tid = threadIdx.x, wv = tid >> 6, lane = tid & 63;
    V[tid] = v[(size_t)n * 256 + tid];
    __syncthreads();
    float4 vv = ((const float4*)V)[lane];
    int cl = clen[n];
    float acc = 0.f;
    for (int s = wv; s < SS; s += 4) {
        float4 cx = ((const float4*)(common_x + ((size_t)n * SS + s) * HD))[lane];
        float d = cx.x * vv.x + cx.y * vv.y + cx.z * vv.z + cx.w * vv.w;
#pragma unroll
        for (int off = 32; off; off >>= 1) d += __shfl_xor(d, off);
        if (lane == 0 && s < cl) {
            float sp = (d > 20.f) ? d : log1pf(__expf(d));
            acc += sp * __expf(-common_time[n * SS + s]);
        }
    }
    if (lane == 0) partial[wv] = acc;
    __syncthreads();
    if (tid == 0) tf[n] = partial[0] + partial[1] + partial[2] + partial[3];
}

// ---------------------------------------------------------------------------
// softmax over padded MAXF (invalid logits exactly 0) + weighted sum.
// ---------------------------------------------------------------------------
__global__ __launch_bounds__(256)
void out_kernel(const float* __restrict__ tf, const int* __restrict__ fnum,
                const float* __restrict__ fl, float* __restrict__ out) {
    __shared__ float e[32];
    __shared__ float tfm[32];
    __shared__ float Zs;
    int b = blockIdx.x, tid = threadIdx.x;
    int nv = fnum[b];
    if (tid < 32) tfm[tid] = (tid < nv) ? tf[b * 32 + tid] : 0.f;
    __syncthreads();
    if (tid == 0) {
        float m = tfm[0];
        for (int f = 1; f < 32; f++) m = fmaxf(m, tfm[f]);
        float Z = 0.f;
        for (int f = 0; f < 32; f++) { e[f] = __expf(tfm[f] - m); Z += e[f]; }
        Zs = Z;
    }
    __syncthreads();
    float Zi = 1.f / Zs;
    float o = 0.f;
    for (int f = 0; f < nv; f++)
        o += e[f] * Zi * fl[((size_t)(b * 32 + f)) * 256 + tid];
    out[b * 256 + tid] = o;
}

// ---------------------------------------------------------------------------
extern "C" void kernel_launch(void* const* d_in, const int* in_sizes, int n_in,
                              void* d_out, int out_size, void* d_ws, size_t ws_size,
                              hipStream_t stream) {
    (void)in_sizes; (void)n_in; (void)out_size; (void)ws_size;
    const float* self_x      = (const float*)d_in[0];
    const float* common_x    = (const float*)d_in[1];
    const float* common_time = (const float*)d_in[2];
    const float* friend_x    = (const float*)d_in[3];
    const float* Wih0 = (const float*)d_in[4];
    const float* Whh0 = (const float*)d_in[5];
    const float* bih0 = (const float*)d_in[6];
    const float* bhh0 = (const float*)d_in[7];
    const float* Wih1 = (const float*)d_in[8];
    const float* Whh1 = (const float*)d_in[9];
    const float* bih1 = (const float*)d_in[10];
    const float* bhh1 = (const float*)d_in[11];
    const float* Wf   = (const float*)d_in[12];
    const float* Wb   = (const float*)d_in[13];
    const int* flen   = (const int*)d_in[14];
    const int* fnum   = (const int*)d_in[15];
    const int* clen   = (const int*)d_in[16];
    float* out = (float*)d_out;

    char* ws = (char*)d_ws;
    unsigned short* wpk = (unsigned short*)ws; ws += (size_t)1572864 * 2;
    float* WfT = (float*)ws;  ws += (size_t)512 * 256 * 4;
    int*   sid = (int*)ws;    ws += (size_t)2048 * 4;
    float* fl  = (float*)ws;  ws += (size_t)2048 * 256 * 4;
    float* vv  = (float*)ws;  ws += (size_t)2048 * 256 * 4;
    float* tf  = (float*)ws;  ws += (size_t)2048 * 4;

    pack_kernel<<<6656, 256, 0, stream>>>(Wih0, Whh0, Wih1, Whh1, Wf, wpk, WfT);
    sort_kernel<<<1, 256, 0, stream>>>(flen, sid);
    gru_kernel<<<NBLK, 1024, 0, stream>>>(friend_x, flen, sid, wpk,
                                          bih0, bhh0, bih1, bhh1, fl);
    sfv_kernel<<<64, 256, 0, stream>>>(self_x, fl, WfT, Wb, vv);
    tf_kernel<<<2048, 256, 0, stream>>>(common_x, common_time, clen, vv, tf);
    out_kernel<<<64, 256, 0, stream>>>(tf, fnum, fl, out);
}

// Round 4
// 2763.517 us; speedup vs baseline: 4.8885x; 1.9142x over previous
//
#include <hip/hip_runtime.h>
#include <hip/hip_bf16.h>
#include <stdint.h>

// Problem constants
#define HD    256      // hidden
#define LL    50       // friend seq len
#define SS    50       // common seq len
#define NB    64       // batch
#define MAXF  32
#define NSEQ  2048     // NB*MAXF
#define MB    32       // sequences per block (one 32-row MFMA M-tile)
#define NBLK  64       // NSEQ/MB
#define XP    264      // padded LDS row (bf16 elems): 528B rows, 16B aligned

typedef __attribute__((ext_vector_type(8)))  short bf16x8;
typedef __attribute__((ext_vector_type(16))) float f32x16;
typedef __attribute__((ext_vector_type(4)))  unsigned short u16x4;

__device__ __forceinline__ f32x16 mfma32(bf16x8 a, bf16x8 b, f32x16 c) {
    return __builtin_amdgcn_mfma_f32_32x32x16_bf16(a, b, c, 0, 0, 0);
}

__device__ __forceinline__ unsigned short f2bf_rne(float f) {
    union { float f; uint32_t u; } v; v.f = f;
    uint32_t u = v.u;
    uint32_t r = u + 0x7FFFu + ((u >> 16) & 1u);
    return (unsigned short)(r >> 16);
}
__device__ __forceinline__ float bf2f(unsigned short b) {
    union { float f; uint32_t u; } v; v.u = ((uint32_t)b) << 16;
    return v.f;
}

// ---------------------------------------------------------------------------
// Pack weights -> per-wave MFMA 32x32x16 fragment stream + Wf^T.
// wpk index = (((wv*2+l)*2 + m)*16 + ks)*6144 + fr*512 + lane*8 + j
//   fr = gate*4 + sub*2 + plane  (gate r/z/n, sub = col-subtile, plane hi/lo)
//   W row n = gate*256 + wv*64 + sub*32 + (lane&31)
//   k       = ks*16 + (lane>>5)*8 + j
// ---------------------------------------------------------------------------
__global__ void pack_kernel(const float* __restrict__ Wih0, const float* __restrict__ Whh0,
                            const float* __restrict__ Wih1, const float* __restrict__ Whh1,
                            const float* __restrict__ Wf,
                            unsigned short* __restrict__ wpk,
                            float* __restrict__ WfT) {
    int idx = blockIdx.x * blockDim.x + threadIdx.x;
    const int TOTW = 1572864;
    if (idx < TOTW) {
        int j    = idx & 7;
        int lane = (idx >> 3) & 63;
        int fr   = (idx >> 9) % 12;
        int t2   = (idx >> 9) / 12;          // ((wv*2+l)*2+m)*16+ks
        int ks   = t2 & 15;
        int m    = (t2 >> 4) & 1;
        int l    = (t2 >> 5) & 1;
        int wvv  = t2 >> 6;
        int gate = fr >> 2, sub = (fr >> 1) & 1, plane = fr & 1;
        const float* W = (l == 0) ? (m == 0 ? Wih0 : Whh0)
                                  : (m == 0 ? Wih1 : Whh1);
        int n = gate * 256 + wvv * 64 + sub * 32 + (lane & 31);
        int k = ks * 16 + (lane >> 5) * 8 + j;
        float v = W[n * HD + k];
        unsigned short hi = f2bf_rne(v);
        wpk[idx] = plane ? f2bf_rne(v - bf2f(hi)) : hi;
    } else {
        int idx2 = idx - TOTW;
        if (idx2 < 512 * 256) {              // WfT[k][h] = Wf[h][k]
            int k = idx2 >> 8; int h = idx2 & 255;
            WfT[k * 256 + h] = Wf[h * 512 + k];
        }
    }
}

// ---------------------------------------------------------------------------
// Counting sort of the 2048 sequences by friend_len (1..50), ascending.
// ---------------------------------------------------------------------------
__global__ void sort_kernel(const int* __restrict__ flen, int* __restrict__ sid) {
    __shared__ int hist[64];
    __shared__ int offs[64];
    int tid = threadIdx.x;
    if (tid < 64) hist[tid] = 0;
    __syncthreads();
    for (int i = tid; i < NSEQ; i += blockDim.x) atomicAdd(&hist[flen[i]], 1);
    __syncthreads();
    if (tid == 0) {
        int acc = 0;
        for (int v = 1; v <= 50; v++) { offs[v] = acc; acc += hist[v]; }
    }
    __syncthreads();
    for (int i = tid; i < NSEQ; i += blockDim.x) {
        int pos = atomicAdd(&offs[flen[i]], 1);
        sid[pos] = i;
    }
}

// ---------------------------------------------------------------------------
// Fused 2-layer GRU. 256 threads = 4 waves, 1 block/CU (LDS-forced), 512-VGPR
// budget via amdgpu_waves_per_eu(1,1). mfma_f32_32x32x16_bf16; wave w owns
// gate columns [64w, 64w+64) of each gate (2 col-subtiles). Split-bf16
// (hi+lo) 3-term MFMA. Weight stream double-buffered (depth-1 prefetch).
// ---------------------------------------------------------------------------
__global__ __launch_bounds__(256) __attribute__((amdgpu_waves_per_eu(1, 1)))
void gru_kernel(const float* __restrict__ friend_x,
                const int* __restrict__ flen,
                const int* __restrict__ sid,
                const unsigned short* __restrict__ wpk,
                const float* __restrict__ bih0, const float* __restrict__ bhh0,
                const float* __restrict__ bih1, const float* __restrict__ bhh1,
                float* __restrict__ friend_last) {
    __shared__ __align__(16) unsigned short Xhi[MB][XP],  Xlo[MB][XP];
    __shared__ __align__(16) unsigned short H0hi[MB][XP], H0lo[MB][XP];
    __shared__ __align__(16) unsigned short H1hi[MB][XP], H1lo[MB][XP];
    __shared__ int sidS[MB], lenS[MB];

    const int tid  = threadIdx.x;
    const int g    = blockIdx.x;
    const int wv   = tid >> 6;          // 0..3
    const int lane = tid & 63;
    const int l31  = lane & 31;
    const int half = lane >> 5;

    if (tid < MB) {
        int s_ = sid[g * MB + tid];
        sidS[tid] = s_;
        lenS[tid] = flen[s_];
    }
    for (int i = tid; i < MB * XP / 2; i += 256) {
        ((uint32_t*)&H0hi[0][0])[i] = 0; ((uint32_t*)&H0lo[0][0])[i] = 0;
        ((uint32_t*)&H1hi[0][0])[i] = 0; ((uint32_t*)&H1lo[0][0])[i] = 0;
    }
    __syncthreads();

    int maxlen = 0;
#pragma unroll
    for (int s = 0; s < MB; s++) maxlen = max(maxlen, lenS[s]);

    const int j0 = wv * 64 + l31;       // this lane's first gate column

    // biases (acc-init values); n-gate input/hidden kept separate
    float b0R[2], b0Z[2], b0Ni[2], b0Nh[2];
    float b1R[2], b1Z[2], b1Ni[2], b1Nh[2];
#pragma unroll
    for (int sub = 0; sub < 2; sub++) {
        int j = j0 + 32 * sub;
        b0R[sub]  = bih0[j] + bhh0[j];
        b0Z[sub]  = bih0[256 + j] + bhh0[256 + j];
        b0Ni[sub] = bih0[512 + j];
        b0Nh[sub] = bhh0[512 + j];
        b1R[sub]  = bih1[j] + bhh1[j];
        b1Z[sub]  = bih1[256 + j] + bhh1[256 + j];
        b1Ni[sub] = bih1[512 + j];
        b1Nh[sub] = bhh1[512 + j];
    }

    int srow[8];                        // staged sequence ids (rows wv*8..wv*8+7)
#pragma unroll
    for (int r = 0; r < 8; r++) srow[r] = sidS[wv * 8 + r];

    float h0c[2][16], h1c[2][16];       // fp32 hidden-state carry [sub][reg]
#pragma unroll
    for (int sub = 0; sub < 2; sub++)
#pragma unroll
        for (int rg = 0; rg < 16; rg++) { h0c[sub][rg] = 0.f; h1c[sub][rg] = 0.f; }

    const int fragBase = l31 * XP + half * 8;

    auto loadB12 = [&](bf16x8* B, const unsigned short* p) {
#pragma unroll
        for (int f = 0; f < 12; f++) B[f] = *(const bf16x8*)(p + f * 512);
    };

    auto compute9 = [&](const bf16x8* B, bf16x8 ah, bf16x8 al,
                        f32x16* aR, f32x16* aZ, f32x16* aN) {
#pragma unroll
        for (int sub = 0; sub < 2; sub++) {
            aR[sub] = mfma32(ah, B[sub * 2],     aR[sub]);
            aR[sub] = mfma32(al, B[sub * 2],     aR[sub]);
            aR[sub] = mfma32(ah, B[sub * 2 + 1], aR[sub]);
            aZ[sub] = mfma32(ah, B[4 + sub * 2],     aZ[sub]);
            aZ[sub] = mfma32(al, B[4 + sub * 2],     aZ[sub]);
            aZ[sub] = mfma32(ah, B[4 + sub * 2 + 1], aZ[sub]);
            aN[sub] = mfma32(ah, B[8 + sub * 2],     aN[sub]);
            aN[sub] = mfma32(al, B[8 + sub * 2],     aN[sub]);
            aN[sub] = mfma32(ah, B[8 + sub * 2 + 1], aN[sub]);
        }
    };

    // one m-phase (16 K-steps) of a layer: A from (Ah,Al), weights at pm
    auto halfMM = [&](const unsigned short* pm,
                      const unsigned short* Ah_, const unsigned short* Al_,
                      f32x16* aR, f32x16* aZ, f32x16* aN) {
        bf16x8 B0[12], B1[12], ah0, al0, ah1, al1;
        loadB12(B0, pm);
        ah0 = *(const bf16x8*)(Ah_ + fragBase);
        al0 = *(const bf16x8*)(Al_ + fragBase);
        loadB12(B1, pm + 6144);
        ah1 = *(const bf16x8*)(Ah_ + fragBase + 16);
        al1 = *(const bf16x8*)(Al_ + fragBase + 16);
#pragma unroll 1
        for (int ks = 0; ks < 16; ks += 2) {
            compute9(B0, ah0, al0, aR, aZ, aN);
            if (ks + 2 < 16) {
                loadB12(B0, pm + (size_t)(ks + 2) * 6144);
                ah0 = *(const bf16x8*)(Ah_ + fragBase + (ks + 2) * 16);
                al0 = *(const bf16x8*)(Al_ + fragBase + (ks + 2) * 16);
            }
            compute9(B1, ah1, al1, aR, aZ, aN);
            if (ks + 3 < 16) {
                loadB12(B1, pm + (size_t)(ks + 3) * 6144);
                ah1 = *(const bf16x8*)(Ah_ + fragBase + (ks + 3) * 16);
                al1 = *(const bf16x8*)(Al_ + fragBase + (ks + 3) * 16);
            }
        }
    };

    auto initAcc = [&](f32x16* a, const float* b) {
#pragma unroll
        for (int sub = 0; sub < 2; sub++) {
            f32x16 v;
#pragma unroll
            for (int i = 0; i < 16; i++) v[i] = b[sub];
            a[sub] = v;
        }
    };

    // gate epilogue; C-layout: col = lane&31 (+32*sub), row = (reg&3)+8*(reg>>2)+4*half
    auto epi = [&](f32x16* aR, f32x16* aZ, f32x16* aNi, f32x16* aNh,
                   float (*hc)[16],
                   unsigned short (*Ohi)[XP], unsigned short (*Olo)[XP],
                   bool gather, int t) {
#pragma unroll
        for (int sub = 0; sub < 2; sub++) {
            const int j = j0 + 32 * sub;
#pragma unroll
            for (int rg = 0; rg < 16; rg++) {
                const int row = (rg & 3) + ((rg >> 2) << 3) + (half << 2);
                float rr = 1.f / (1.f + __expf(-aR[sub][rg]));
                float zz = 1.f / (1.f + __expf(-aZ[sub][rg]));
                float nx = aNi[sub][rg] + rr * aNh[sub][rg];
                float e  = __expf(-2.f * fabsf(nx));
                float th = 1.f - 2.f * e / (1.f + e);
                th = (nx < 0.f) ? -th : th;
                float hNew = (1.f - zz) * th + zz * hc[sub][rg];
                hc[sub][rg] = hNew;
                unsigned short hi_ = f2bf_rne(hNew);
                Ohi[row][j] = hi_;
                Olo[row][j] = f2bf_rne(hNew - bf2f(hi_));
                if (gather && t == lenS[row] - 1)
                    friend_last[(size_t)sidS[row] * HD + j] = hNew;
            }
        }
    };

    auto stageWrite = [&](const float4* sx) {
#pragma unroll
        for (int r = 0; r < 8; r++) {
            int row = wv * 8 + r;
            float vals[4] = { sx[r].x, sx[r].y, sx[r].z, sx[r].w };
            u16x4 hi4, lo4;
#pragma unroll
            for (int e2 = 0; e2 < 4; e2++) {
                unsigned short h_ = f2bf_rne(vals[e2]);
                hi4[e2] = h_;
                lo4[e2] = f2bf_rne(vals[e2] - bf2f(h_));
            }
            *(u16x4*)&Xhi[row][lane * 4] = hi4;
            *(u16x4*)&Xlo[row][lane * 4] = lo4;
        }
    };

    // stage x(0)
    {
        float4 sx[8];
#pragma unroll
        for (int r = 0; r < 8; r++)
            sx[r] = ((const float4*)(friend_x + ((size_t)srow[r] * LL) * HD))[lane];
        stageWrite(sx);
    }
    __syncthreads();

    // per-wave weight bases: (wv*2+l)*196608 ; +m*98304 for the m-phase
    const unsigned short* pw0 = wpk + (size_t)(wv * 2 + 0) * 196608 + (size_t)lane * 8;
    const unsigned short* pw1 = wpk + (size_t)(wv * 2 + 1) * 196608 + (size_t)lane * 8;

    for (int t = 0; t < maxlen; t++) {
        // issue next-step staging loads early (held in regs through layer 0)
        int tn = (t + 1 < maxlen) ? t + 1 : t;
        float4 sx[8];
#pragma unroll
        for (int r = 0; r < 8; r++)
            sx[r] = ((const float4*)(friend_x + ((size_t)srow[r] * LL + tn) * HD))[lane];

        // ---- Layer 0: gates = x(t)·Wih0 + h0·Whh0 ----
        f32x16 aR[2], aZ[2], aNi[2], aNh[2];
        initAcc(aR, b0R); initAcc(aZ, b0Z); initAcc(aNi, b0Ni); initAcc(aNh, b0Nh);
        halfMM(pw0,         &Xhi[0][0],  &Xlo[0][0],  aR, aZ, aNi);
        halfMM(pw0 + 98304, &H0hi[0][0], &H0lo[0][0], aR, aZ, aNh);
        __syncthreads();                       // B1: X/H0 reads complete
        epi(aR, aZ, aNi, aNh, h0c, H0hi, H0lo, false, t);
        stageWrite(sx);                        // write x(t+1)
        __syncthreads();                       // B2: h0(t) + x(t+1) visible
        // ---- Layer 1: gates = h0(t)·Wih1 + h1·Whh1 ----
        initAcc(aR, b1R); initAcc(aZ, b1Z); initAcc(aNi, b1Ni); initAcc(aNh, b1Nh);
        halfMM(pw1,         &H0hi[0][0], &H0lo[0][0], aR, aZ, aNi);
        halfMM(pw1 + 98304, &H1hi[0][0], &H1lo[0][0], aR, aZ, aNh);
        __syncthreads();                       // B3: H0/H1 reads complete
        epi(aR, aZ, aNi, aNh, h1c, H1hi, H1lo, true, t);
    }
}

// ---------------------------------------------------------------------------
// Fused: sf[n,h] = Wf[h,:256]·self_x[b] + Wf[h,256:]·fl[n]; v[n,h] = Wb[:,h]·sf[n,:]
// ---------------------------------------------------------------------------
__global__ __launch_bounds__(256)
void sfv_kernel(const float* __restrict__ self_x, const float* __restrict__ fl,
                const float* __restrict__ WfT, const float* __restrict__ Wb,
                float* __restrict__ vout) {
    __shared__ float S[256];
    __shared__ float T[256][33];   // phase1: fl^T [k][f]; phase2: sf^T [g][f]
    int b = blockIdx.x, tid = threadIdx.x;
    S[tid] = self_x[b * 256 + tid];
    for (int i = tid; i < 32 * 256; i += 256) {
        int f = i >> 8, k = i & 255;
        T[k][f] = fl[((size_t)(b * 32 + f)) * 256 + k];
    }
    __syncthreads();
    float acc0 = 0.f;
    for (int k = 0; k < 256; k++) acc0 += WfT[k * 256 + tid] * S[k];
    float acc[32];
#pragma unroll
    for (int f = 0; f < 32; f++) acc[f] = acc0;
    for (int k = 0; k < 256; k++) {
        float w = WfT[(256 + k) * 256 + tid];
#pragma unroll
        for (int f = 0; f < 32; f++) acc[f] += w * T[k][f];
    }
    __syncthreads();
#pragma unroll
    for (int f = 0; f < 32; f++) T[tid][f] = acc[f];   // sf^T into LDS
    __syncthreads();
    float av[32];
#pragma unroll
    for (int f = 0; f < 32; f++) av[f] = 0.f;
    for (int gg = 0; gg < 256; gg++) {
        float w = Wb[gg * 256 + tid];
#pragma unroll
        for (int f = 0; f < 32; f++) av[f] += w * T[gg][f];
    }
#pragma unroll
    for (int f = 0; f < 32; f++)
        vout[((size_t)(b * 32 + f)) * 256 + tid] = av[f];
}

// ---------------------------------------------------------------------------
// tf[n] = sum_s softplus(common_x[n,s,:]·v[n,:]) * exp(-time) * (s < clen)
// ---------------------------------------------------------------------------
__global__ __launch_bounds__(256)
void tf_kernel(const float* __restrict__ common_x, const float* __restrict__ common_time,
               const int* __restrict__ clen, const float* __restrict__ v,
               float* __restrict__ tf) {
    __shared__ float V[256];
    __shared__ float partial[4];
    int n = blockIdx.x, tid = threadIdx.x, wv = tid >> 6, lane = tid & 63;
    V[tid] = v[(size_t)n * 256 + tid];
    __syncthreads();
    float4 vv = ((const float4*)V)[lane];
    int cl = clen[n];
    float acc = 0.f;
    for (int s = wv; s < SS; s += 4) {
        float4 cx = ((const float4*)(common_x + ((size_t)n * SS + s) * HD))[lane];
        float d = cx.x * vv.x + cx.y * vv.y + cx.z * vv.z + cx.w * vv.w;
#pragma unroll
        for (int off = 32; off; off >>= 1) d += __shfl_xor(d, off);
        if (lane == 0 && s < cl) {
            float sp = (d > 20.f) ? d : log1pf(__expf(d));
            acc += sp * __expf(-common_time[n * SS + s]);
        }
    }
    if (lane == 0) partial[wv] = acc;
    __syncthreads();
    if (tid == 0) tf[n] = partial[0] + partial[1] + partial[2] + partial[3];
}

// ---------------------------------------------------------------------------
// softmax over padded MAXF (invalid logits exactly 0) + weighted sum.
// ---------------------------------------------------------------------------
__global__ __launch_bounds__(256)
void out_kernel(const float* __restrict__ tf, const int* __restrict__ fnum,
                const float* __restrict__ fl, float* __restrict__ out) {
    __shared__ float e[32];
    __shared__ float tfm[32];
    __shared__ float Zs;
    int b = blockIdx.x, tid = threadIdx.x;
    int nv = fnum[b];
    if (tid < 32) tfm[tid] = (tid < nv) ? tf[b * 32 + tid] : 0.f;
    __syncthreads();
    if (tid == 0) {
        float m = tfm[0];
        for (int f = 1; f < 32; f++) m = fmaxf(m, tfm[f]);
        float Z = 0.f;
        for (int f = 0; f < 32; f++) { e[f] = __expf(tfm[f] - m); Z += e[f]; }
        Zs = Z;
    }
    __syncthreads();
    float Zi = 1.f / Zs;
    float o = 0.f;
    for (int f = 0; f < nv; f++)
        o += e[f] * Zi * fl[((size_t)(b * 32 + f)) * 256 + tid];
    out[b * 256 + tid] = o;
}

// ---------------------------------------------------------------------------
extern "C" void kernel_launch(void* const* d_in, const int* in_sizes, int n_in,
                              void* d_out, int out_size, void* d_ws, size_t ws_size,
                              hipStream_t stream) {
    (void)in_sizes; (void)n_in; (void)out_size; (void)ws_size;
    const float* self_x      = (const float*)d_in[0];
    const float* common_x    = (const float*)d_in[1];
    const float* common_time = (const float*)d_in[2];
    const float* friend_x    = (const float*)d_in[3];
    const float* Wih0 = (const float*)d_in[4];
    const float* Whh0 = (const float*)d_in[5];
    const float* bih0 = (const float*)d_in[6];
    const float* bhh0 = (const float*)d_in[7];
    const float* Wih1 = (const float*)d_in[8];
    const float* Whh1 = (const float*)d_in[9];
    const float* bih1 = (const float*)d_in[10];
    const float* bhh1 = (const float*)d_in[11];
    const float* Wf   = (const float*)d_in[12];
    const float* Wb   = (const float*)d_in[13];
    const int* flen   = (const int*)d_in[14];
    const int* fnum   = (const int*)d_in[15];
    const int* clen   = (const int*)d_in[16];
    float* out = (float*)d_out;

    char* ws = (char*)d_ws;
    unsigned short* wpk = (unsigned short*)ws; ws += (size_t)1572864 * 2;
    float* WfT = (float*)ws;  ws += (size_t)512 * 256 * 4;
    int*   sid = (int*)ws;    ws += (size_t)2048 * 4;
    float* fl  = (float*)ws;  ws += (size_t)2048 * 256 * 4;
    float* vv  = (float*)ws;  ws += (size_t)2048 * 256 * 4;
    float* tf  = (float*)ws;  ws += (size_t)2048 * 4;

    pack_kernel<<<6656, 256, 0, stream>>>(Wih0, Whh0, Wih1, Whh1, Wf, wpk, WfT);
    sort_kernel<<<1, 256, 0, stream>>>(flen, sid);
    gru_kernel<<<NBLK, 256, 0, stream>>>(friend_x, flen, sid, wpk,
                                         bih0, bhh0, bih1, bhh1, fl);
    sfv_kernel<<<64, 256, 0, stream>>>(self_x, fl, WfT, Wb, vv);
    tf_kernel<<<2048, 256, 0, stream>>>(common_x, common_time, clen, vv, tf);
    out_kernel<<<64, 256, 0, stream>>>(tf, fnum, fl, out);
}